// Round 2
// baseline (344.463 us; speedup 1.0000x reference)
//
#include <hip/hip_runtime.h>

#define NQ   10000
#define BSZ  2
#define DIM  256
#define NH   8
#define HD   32
#define NLV  4
#define NPT  4
#define NV   13294           // 10000 + 2500 + 625 + 169
#define MT   (BSZ*NQ)        // 20000 rows
#define NOUT 384             // 256 offsets + 128 attn logits

typedef float  floatx4 __attribute__((ext_vector_type(4)));
typedef __bf16 bf16x8  __attribute__((ext_vector_type(8)));

__device__ __forceinline__ unsigned short f32_to_bf16(float f) {
  unsigned int u = __float_as_uint(f);
  u += 0x7FFFu + ((u >> 16) & 1u);   // RNE
  return (unsigned short)(u >> 16);
}

// ---------------- cast Q and [W_off;W_attn] to bf16 ----------------
__global__ __launch_bounds__(256) void cast_kernel(
    const float* __restrict__ query, const float* __restrict__ W_off,
    const float* __restrict__ W_attn,
    unsigned short* __restrict__ Qb, unsigned short* __restrict__ Wb) {
  int i = blockIdx.x * 256 + threadIdx.x;
  if (i < 5120000) {
    Qb[i] = f32_to_bf16(query[i]);
  } else if (i < 5218304) {
    int j = i - 5120000;
    float v = (j < 65536) ? W_off[j] : W_attn[j - 65536];
    Wb[j] = f32_to_bf16(v);
  }
}

// ---------------- bf16 MFMA GEMM: raw = Q @ Wcat^T + bias ----------------
// block tile 64(m) x 64(n), BK=32, 4 waves; wave w owns m-rows [w*16, w*16+16)
__global__ __launch_bounds__(256) void gemm_kernel(
    const unsigned short* __restrict__ Qb, const unsigned short* __restrict__ Wb,
    const float* __restrict__ b_off, const float* __restrict__ b_attn,
    float* __restrict__ raw) {
  __shared__ unsigned short As[64][40];   // +8 pad: breaks bank aliasing, keeps 16B align
  __shared__ unsigned short Bs[64][40];
  const int m0 = blockIdx.x * 64;
  const int n0 = blockIdx.y * 64;
  const int tid  = threadIdx.x;
  const int wave = tid >> 6;
  const int lane = tid & 63;
  const int quad = lane >> 4;
  const int l16  = lane & 15;
  floatx4 acc[4] = {{0.f,0.f,0.f,0.f},{0.f,0.f,0.f,0.f},
                    {0.f,0.f,0.f,0.f},{0.f,0.f,0.f,0.f}};
  const int ar = tid >> 2;        // 0..63
  const int ac = (tid & 3) * 8;   // 0,8,16,24

  for (int k0 = 0; k0 < DIM; k0 += 32) {
    int gm = m0 + ar;
    uint4 av = make_uint4(0u,0u,0u,0u);
    if (gm < MT) av = *(const uint4*)&Qb[gm*DIM + k0 + ac];
    uint4 bv = *(const uint4*)&Wb[(n0 + ar)*DIM + k0 + ac];
    *(uint4*)&As[ar][ac] = av;
    *(uint4*)&Bs[ar][ac] = bv;
    __syncthreads();
    // A frag: A[m=l16][k=quad*8+j]  (16B contiguous)
    bf16x8 a = *(const bf16x8*)&As[wave*16 + l16][quad*8];
    #pragma unroll
    for (int nt = 0; nt < 4; nt++) {
      // B frag: B[k=quad*8+j][n=l16] = Wcat[n][k]  (16B contiguous)
      bf16x8 b = *(const bf16x8*)&Bs[nt*16 + l16][quad*8];
      acc[nt] = __builtin_amdgcn_mfma_f32_16x16x32_bf16(a, b, acc[nt], 0, 0, 0);
    }
    __syncthreads();
  }
  // C/D layout: row = quad*4 + r, col = l16
  #pragma unroll
  for (int nt = 0; nt < 4; nt++) {
    int gn = n0 + nt*16 + l16;
    float bias = (gn < 256) ? b_off[gn] : b_attn[gn - 256];
    #pragma unroll
    for (int r = 0; r < 4; r++) {
      int gm = m0 + wave*16 + quad*4 + r;
      if (gm < MT) raw[gm*NOUT + gn] = acc[nt][r] + bias;
    }
  }
}

// ---------------- softmax + bilinear sampling, one block per (b,q) ----------------
__global__ __launch_bounds__(256) void sample_kernel(
    const float* __restrict__ raw, const float* __restrict__ value,
    const float* __restrict__ refp, float* __restrict__ tmp) {
  const int q = blockIdx.x;
  const int b = blockIdx.y;
  const int m = b * NQ + q;
  __shared__ float s_px[128], s_py[128], s_logit[128], s_aw[128];
  __shared__ float s_w[128][4];
  __shared__ int   s_idx[128][4];
  const int tid = threadIdx.x;

  if (tid < 128) {   // one thread per (h,l,p)
    const int h = tid >> 4, r = tid & 15, l = r >> 2, p = r & 3;
    const int WL[4] = {100, 50, 25, 13};
    // off layout: (NH, NL*NP*2) -> h*32 + l*8 + p*2 + xy   [R1 fix: was h*64]
    float offx = raw[m*NOUT + h*32 + l*8 + p*2 + 0];
    float offy = raw[m*NOUT + h*32 + l*8 + p*2 + 1];
    s_logit[tid] = raw[m*NOUT + 256 + h*16 + l*4 + p];
    float rx = refp[(m*NLV + l)*2 + 0];
    float ry = refp[(m*NLV + l)*2 + 1];
    float Wl = (float)WL[l];
    // (ref + off/W)*2-1 -> pixel coords (align_corners=False): ref*W + off - 0.5
    s_px[tid] = rx * Wl + offx - 0.5f;
    s_py[tid] = ry * Wl + offy - 0.5f;
  }
  __syncthreads();
  if (tid < NH) {    // softmax over 16 logits per head
    float mx = -1e30f;
    for (int i = 0; i < 16; i++) mx = fmaxf(mx, s_logit[tid*16 + i]);
    float s = 0.f;
    for (int i = 0; i < 16; i++) {
      float e = expf(s_logit[tid*16 + i] - mx);
      s_aw[tid*16 + i] = e; s += e;
    }
    float inv = 1.f / s;
    for (int i = 0; i < 16; i++) s_aw[tid*16 + i] *= inv;
  }
  __syncthreads();
  if (tid < 128) {   // bilinear taps (weights pre-multiplied by aw)
    const int r = tid & 15, l = r >> 2;
    const int WL[4] = {100, 50, 25, 13};
    const int ST[4] = {0, 10000, 12500, 13125};
    int Wl = WL[l];
    float px = s_px[tid], py = s_py[tid];
    float x0f = floorf(px), y0f = floorf(py);
    int x0 = (int)x0f, y0 = (int)y0f;
    float wx1 = px - x0f, wx0 = 1.f - wx1;
    float wy1 = py - y0f, wy0 = 1.f - wy1;
    float aw = s_aw[tid];
    #pragma unroll
    for (int t = 0; t < 4; t++) {
      int xi = x0 + (t & 1), yi = y0 + (t >> 1);
      bool inb = (xi >= 0) && (xi < Wl) && (yi >= 0) && (yi < Wl);
      s_idx[tid][t] = inb ? (ST[l] + yi*Wl + xi) : -1;
      float w = ((t & 1) ? wx1 : wx0) * ((t >> 1) ? wy1 : wy0);
      s_w[tid][t] = inb ? (aw * w) : 0.f;
    }
  }
  __syncthreads();
  // accumulate: thread (h,c), 16 points x 4 taps
  const int h = tid >> 5, c = tid & 31;
  float acc = 0.f;
  #pragma unroll 4
  for (int pt = 0; pt < 16; pt++) {
    int base = h*16 + pt;
    #pragma unroll
    for (int t = 0; t < 4; t++) {
      int idx = s_idx[base][t];
      float w = s_w[base][t];
      if (idx >= 0) acc += w * value[((long)(b*NV + idx)*NH + h)*HD + c];
    }
  }
  tmp[(long)m*DIM + h*HD + c] = acc;  // [b,q,ch] coalesced
}

// ---------------- transpose tmp[b,q,ch] -> out[b,ch,q] ----------------
__global__ __launch_bounds__(256) void transpose_kernel(
    const float* __restrict__ tmp, float* __restrict__ out) {
  __shared__ float tile[32][33];
  const int b  = blockIdx.z;
  const int q0 = blockIdx.x * 32;
  const int c0 = blockIdx.y * 32;
  const int tx = threadIdx.x & 31;
  const int ty = threadIdx.x >> 5;   // 0..7
  #pragma unroll
  for (int i = 0; i < 4; i++) {
    int qq = q0 + ty + i*8;
    tile[ty + i*8][tx] = (qq < NQ) ? tmp[((long)b*NQ + qq)*DIM + c0 + tx] : 0.f;
  }
  __syncthreads();
  if (q0 + tx < NQ) {
    #pragma unroll
    for (int i = 0; i < 4; i++) {
      out[((long)b*DIM + c0 + ty + i*8)*NQ + q0 + tx] = tile[tx][ty + i*8];
    }
  }
}

extern "C" void kernel_launch(void* const* d_in, const int* in_sizes, int n_in,
                              void* d_out, int out_size, void* d_ws, size_t ws_size,
                              hipStream_t stream) {
  const float* query  = (const float*)d_in[0];
  const float* value  = (const float*)d_in[1];
  const float* refp   = (const float*)d_in[2];
  // d_in[3] = spatial_shapes (constants hardcoded)
  const float* W_off  = (const float*)d_in[4];
  const float* b_off  = (const float*)d_in[5];
  const float* W_attn = (const float*)d_in[6];
  const float* b_attn = (const float*)d_in[7];
  float* out = (float*)d_out;

  char* ws = (char*)d_ws;
  // region 0 [0, 20.48MB): Qb (bf16, 10.24MB) during GEMM, then tmp (f32, 20.48MB)
  unsigned short* Qb  = (unsigned short*)ws;
  float*          tmp = (float*)ws;
  unsigned short* Wb  = (unsigned short*)(ws + 20480000);           // 196,608 B
  float*          raw = (float*)(ws + 20480000 + 196608);           // 30,720,000 B

  hipLaunchKernelGGL(cast_kernel, dim3((5218304 + 255) / 256), dim3(256), 0, stream,
                     query, W_off, W_attn, Qb, Wb);
  hipLaunchKernelGGL(gemm_kernel, dim3(313, 6), dim3(256), 0, stream,
                     Qb, Wb, b_off, b_attn, raw);
  hipLaunchKernelGGL(sample_kernel, dim3(NQ, BSZ), dim3(256), 0, stream,
                     raw, value, refp, tmp);
  hipLaunchKernelGGL(transpose_kernel, dim3(313, 8, 2), dim3(256), 0, stream,
                     tmp, out);
}

// Round 3
// 183.178 us; speedup vs baseline: 1.8805x; 1.8805x over previous
//
#include <hip/hip_runtime.h>

#define NQ   10000
#define BSZ  2
#define DIM  256
#define NH   8
#define HD   32
#define NLV  4
#define NPT  4
#define NV   13294           // 10000 + 2500 + 625 + 169
#define MT   (BSZ*NQ)        // 20000 rows
#define NOUT 384             // 256 offsets + 128 attn logits

typedef float  floatx4 __attribute__((ext_vector_type(4)));
typedef int    intx4   __attribute__((ext_vector_type(4)));
typedef __bf16 bf16x8  __attribute__((ext_vector_type(8)));

__device__ __forceinline__ unsigned short f32_to_bf16(float f) {
  unsigned int u = __float_as_uint(f);
  u += 0x7FFFu + ((u >> 16) & 1u);   // RNE
  return (unsigned short)(u >> 16);
}

// ---------------- cast Q and [W_off;W_attn] to bf16 ----------------
__global__ __launch_bounds__(256) void cast_kernel(
    const float* __restrict__ query, const float* __restrict__ W_off,
    const float* __restrict__ W_attn,
    unsigned short* __restrict__ Qb, unsigned short* __restrict__ Wb) {
  int i = blockIdx.x * 256 + threadIdx.x;
  if (i < 5120000) {
    Qb[i] = f32_to_bf16(query[i]);
  } else if (i < 5218304) {
    int j = i - 5120000;
    float v = (j < 65536) ? W_off[j] : W_attn[j - 65536];
    Wb[j] = f32_to_bf16(v);
  }
}

// ---------------- bf16 MFMA GEMM: raw = Q @ Wcat^T + bias ----------------
// block tile 64(m) x 64(n), BK=32, 4 waves; wave w owns m-rows [w*16, w*16+16)
__global__ __launch_bounds__(256) void gemm_kernel(
    const unsigned short* __restrict__ Qb, const unsigned short* __restrict__ Wb,
    const float* __restrict__ b_off, const float* __restrict__ b_attn,
    float* __restrict__ raw) {
  __shared__ unsigned short As[64][40];
  __shared__ unsigned short Bs[64][40];
  const int m0 = blockIdx.x * 64;
  const int n0 = blockIdx.y * 64;
  const int tid  = threadIdx.x;
  const int wave = tid >> 6;
  const int lane = tid & 63;
  const int quad = lane >> 4;
  const int l16  = lane & 15;
  floatx4 acc[4] = {{0.f,0.f,0.f,0.f},{0.f,0.f,0.f,0.f},
                    {0.f,0.f,0.f,0.f},{0.f,0.f,0.f,0.f}};
  const int ar = tid >> 2;        // 0..63
  const int ac = (tid & 3) * 8;   // 0,8,16,24

  for (int k0 = 0; k0 < DIM; k0 += 32) {
    int gm = m0 + ar;
    uint4 av = make_uint4(0u,0u,0u,0u);
    if (gm < MT) av = *(const uint4*)&Qb[gm*DIM + k0 + ac];
    uint4 bv = *(const uint4*)&Wb[(n0 + ar)*DIM + k0 + ac];
    *(uint4*)&As[ar][ac] = av;
    *(uint4*)&Bs[ar][ac] = bv;
    __syncthreads();
    bf16x8 a = *(const bf16x8*)&As[wave*16 + l16][quad*8];
    #pragma unroll
    for (int nt = 0; nt < 4; nt++) {
      bf16x8 b = *(const bf16x8*)&Bs[nt*16 + l16][quad*8];
      acc[nt] = __builtin_amdgcn_mfma_f32_16x16x32_bf16(a, b, acc[nt], 0, 0, 0);
    }
    __syncthreads();
  }
  #pragma unroll
  for (int nt = 0; nt < 4; nt++) {
    int gn = n0 + nt*16 + l16;
    float bias = (gn < 256) ? b_off[gn] : b_attn[gn - 256];
    #pragma unroll
    for (int r = 0; r < 4; r++) {
      int gm = m0 + wave*16 + quad*4 + r;
      if (gm < MT) raw[gm*NOUT + gn] = acc[nt][r] + bias;
    }
  }
}

// ---------------- softmax + bilinear sampling ----------------
// Block = 256 threads handles FOUR queries. Phases:
//  1) 512 slots (ql,h,l,p): px,py,logit -> LDS
//  2) softmax per (ql,h) over 16 logits (32 threads)
//  3) tap table: byte-offset (incl. h*128; OOB -> 0) and aw-folded weight,
//     row layout [ (ql*8+h)*132 + pt*8 ] = {off0..3, w0..3}
//     132-word row stride: 8 broadcast rows per wave hit disjoint bank quads.
//  4) accumulate: wave=ql, lane=(h,cq): 16 x (2 ds_read_b128 +
//     4 global_load_dwordx4 + 16 fma), float4 acc, coalesced float4 store.
__global__ __launch_bounds__(256) void sample_kernel(
    const float* __restrict__ raw, const float* __restrict__ value,
    const float* __restrict__ refp, float* __restrict__ tmp) {
  const int b  = blockIdx.y;
  const int q0 = blockIdx.x * 4;
  const int mbase = b * NQ + q0;
  const int tid = threadIdx.x;

  __shared__ float s_px[512], s_py[512], s_logit[512];
  __shared__ int   s_tab[4 * 8 * 132];   // 16896 B

  const int WLI[4] = {100, 50, 25, 13};
  const int STI[4] = {0, 10000, 12500, 13125};

  // ---- phase 1: sampling coords + logits ----
  #pragma unroll
  for (int it = 0; it < 2; ++it) {
    int slot = it * 256 + tid;
    int ql = slot >> 7, r = slot & 127, h = r >> 4, lp = r & 15, l = lp >> 2, p = lp & 3;
    int m = mbase + ql;
    const float* rp = raw + m * NOUT;
    float offx = rp[h*32 + l*8 + p*2 + 0];
    float offy = rp[h*32 + l*8 + p*2 + 1];
    s_logit[slot] = rp[256 + h*16 + lp];
    float Wl = (float)WLI[l];
    float rx = refp[(m*NLV + l)*2 + 0];
    float ry = refp[(m*NLV + l)*2 + 1];
    // (ref + off/W)*2-1 -> pixel (align_corners=False): ref*W + off - 0.5
    s_px[slot] = rx * Wl + offx - 0.5f;
    s_py[slot] = ry * Wl + offy - 0.5f;
  }
  __syncthreads();

  // ---- phase 2: softmax over 16 logits per (ql,h), in place ----
  if (tid < 32) {
    int base = tid * 16;   // tid = ql*8+h
    float mx = -1e30f;
    #pragma unroll
    for (int i = 0; i < 16; i++) mx = fmaxf(mx, s_logit[base + i]);
    float s = 0.f;
    float e[16];
    #pragma unroll
    for (int i = 0; i < 16; i++) { e[i] = expf(s_logit[base + i] - mx); s += e[i]; }
    float inv = 1.f / s;
    #pragma unroll
    for (int i = 0; i < 16; i++) s_logit[base + i] = e[i] * inv;
  }
  __syncthreads();

  // ---- phase 3: tap table (byte offsets + folded weights) ----
  #pragma unroll
  for (int it = 0; it < 2; ++it) {
    int slot = it * 256 + tid;
    int ql = slot >> 7, r = slot & 127, h = r >> 4, lp = r & 15, l = lp >> 2;
    float px = s_px[slot], py = s_py[slot], aw = s_logit[slot];
    float x0f = floorf(px), y0f = floorf(py);
    int x0 = (int)x0f, y0 = (int)y0f;
    float wx1 = px - x0f, wx0 = 1.f - wx1;
    float wy1 = py - y0f, wy0 = 1.f - wy1;
    int Wl = WLI[l], STl = STI[l];
    int row = (ql*8 + h) * 132 + lp * 8;
    #pragma unroll
    for (int t = 0; t < 4; ++t) {
      int xi = x0 + (t & 1), yi = y0 + (t >> 1);
      bool inb = (xi >= 0) & (xi < Wl) & (yi >= 0) & (yi < Wl);
      int off = inb ? ((STl + yi*Wl + xi) * 1024 + h * 128) : 0;  // bytes
      float w = inb ? (aw * ((t & 1) ? wx1 : wx0) * ((t >> 1) ? wy1 : wy0)) : 0.f;
      s_tab[row + t]     = off;
      s_tab[row + 4 + t] = __float_as_int(w);
    }
  }
  __syncthreads();

  // ---- phase 4: accumulate; wave = query, lane = (h, cq) ----
  const int ql = tid >> 6, lane = tid & 63, h = lane >> 3, cq = lane & 7;
  const char* vb = (const char*)value + (size_t)b * (NV*NH*HD*4) + cq * 16;
  floatx4 acc = {0.f, 0.f, 0.f, 0.f};
  const int rbase = (ql*8 + h) * 132;
  #pragma unroll 4
  for (int pt = 0; pt < 16; ++pt) {
    intx4   offs = *(const intx4*)  &s_tab[rbase + pt*8];
    floatx4 ws   = *(const floatx4*)&s_tab[rbase + pt*8 + 4];
    floatx4 v0 = *(const floatx4*)(vb + offs.x);
    floatx4 v1 = *(const floatx4*)(vb + offs.y);
    floatx4 v2 = *(const floatx4*)(vb + offs.z);
    floatx4 v3 = *(const floatx4*)(vb + offs.w);
    acc += ws.x * v0;
    acc += ws.y * v1;
    acc += ws.z * v2;
    acc += ws.w * v3;
  }
  int m = mbase + ql;
  *(floatx4*)&tmp[(size_t)m * DIM + h*HD + cq*4] = acc;   // [b,q,ch] coalesced
}

// ---------------- transpose tmp[b,q,ch] -> out[b,ch,q] ----------------
__global__ __launch_bounds__(256) void transpose_kernel(
    const float* __restrict__ tmp, float* __restrict__ out) {
  __shared__ float tile[32][33];
  const int b  = blockIdx.z;
  const int q0 = blockIdx.x * 32;
  const int c0 = blockIdx.y * 32;
  const int tx = threadIdx.x & 31;
  const int ty = threadIdx.x >> 5;   // 0..7
  #pragma unroll
  for (int i = 0; i < 4; i++) {
    int qq = q0 + ty + i*8;
    tile[ty + i*8][tx] = (qq < NQ) ? tmp[((long)b*NQ + qq)*DIM + c0 + tx] : 0.f;
  }
  __syncthreads();
  if (q0 + tx < NQ) {
    #pragma unroll
    for (int i = 0; i < 4; i++) {
      out[((long)b*DIM + c0 + ty + i*8)*NQ + q0 + tx] = tile[tx][ty + i*8];
    }
  }
}

extern "C" void kernel_launch(void* const* d_in, const int* in_sizes, int n_in,
                              void* d_out, int out_size, void* d_ws, size_t ws_size,
                              hipStream_t stream) {
  const float* query  = (const float*)d_in[0];
  const float* value  = (const float*)d_in[1];
  const float* refp   = (const float*)d_in[2];
  // d_in[3] = spatial_shapes (constants hardcoded)
  const float* W_off  = (const float*)d_in[4];
  const float* b_off  = (const float*)d_in[5];
  const float* W_attn = (const float*)d_in[6];
  const float* b_attn = (const float*)d_in[7];
  float* out = (float*)d_out;

  char* ws = (char*)d_ws;
  // region 0 [0, 20.48MB): Qb (bf16, 10.24MB) during GEMM, then tmp (f32, 20.48MB)
  unsigned short* Qb  = (unsigned short*)ws;
  float*          tmp = (float*)ws;
  unsigned short* Wb  = (unsigned short*)(ws + 20480000);           // 196,608 B
  float*          raw = (float*)(ws + 20480000 + 196608);           // 30,720,000 B

  hipLaunchKernelGGL(cast_kernel, dim3((5218304 + 255) / 256), dim3(256), 0, stream,
                     query, W_off, W_attn, Qb, Wb);
  hipLaunchKernelGGL(gemm_kernel, dim3(313, 6), dim3(256), 0, stream,
                     Qb, Wb, b_off, b_attn, raw);
  hipLaunchKernelGGL(sample_kernel, dim3(NQ / 4, BSZ), dim3(256), 0, stream,
                     raw, value, refp, tmp);
  hipLaunchKernelGGL(transpose_kernel, dim3(313, 8, 2), dim3(256), 0, stream,
                     tmp, out);
}